// Round 2
// baseline (111.448 us; speedup 1.0000x reference)
//
#include <hip/hip_runtime.h>
#include <math.h>

#define NF 32
#define NE 64
#define NA 64
#define NP 496
#define XS 68   // padded LDS row stride (floats): 272B, 16B-aligned, spreads banks

__global__ __launch_bounds__(256, 4) void afm_fwd(
    const float* __restrict__ x,    // (B,32,64)
    const float* __restrict__ W1,   // (64,64)
    const float* __restrict__ b1,   // (64)
    const float* __restrict__ w2,   // (64,1)
    const float* __restrict__ b2,   // (1)
    float* __restrict__ out,        // (B,64)
    float* __restrict__ attn)       // (B,496)
{
    const int b    = blockIdx.x;
    const int tid  = threadIdx.x;
    const int lane = tid & 63;
    const int wv   = tid >> 6;

    __shared__ float xs[NF * XS];            // 8704 B
    __shared__ float s_l[512];               // logits -> attn weights
    __shared__ unsigned char s_r[512], s_c[512];
    __shared__ float s_red_m[4], s_red_s[4];
    __shared__ float s_acc[4][NE];

    // ---- stage x[b] into LDS (padded rows) ----
    const float* __restrict__ xb = x + (size_t)b * (NF * NE);
    for (int i = tid; i < NF * NE; i += 256) {
        xs[(i >> 6) * XS + (i & 63)] = xb[i];
    }
    // ---- pair index table (row-major triu k=1, matches np.triu_indices) ----
    for (int p = tid; p < 512; p += 256) {
        int pp = (p < NP) ? p : 0;
        int r = 0;
        while (pp >= 31 - r) { pp -= 31 - r; ++r; }
        s_r[p] = (unsigned char)r;
        s_c[p] = (unsigned char)(r + 1 + pp);
    }
    __syncthreads();

    const float bias2 = b2[0];

    // ---- phase 1: logits. lane = pair; A-dim split in 2 halves of 32 so the
    // accumulator (h[32]) stays register-resident (R0: h[64] spilled @ VGPR=40)
    for (int ck = wv; ck < 8; ck += 4) {
        const int p = (ck << 6) + lane;
        const int r = s_r[p];
        const int c = s_c[p];
        const float* xr = xs + r * XS;
        const float* xc = xs + c * XS;

        float logit = bias2;
        #pragma unroll
        for (int half = 0; half < 2; ++half) {
            const int a0 = half << 5;
            float h[32];
            #pragma unroll
            for (int a = 0; a < 32; ++a) h[a] = b1[a0 + a];   // uniform -> s_load

            for (int e = 0; e < NE; e += 4) {
                const float4 r4 = *(const float4*)(xr + e);   // ds_read_b128
                const float4 c4 = *(const float4*)(xc + e);
                const float ie0 = r4.x * c4.x;
                const float ie1 = r4.y * c4.y;
                const float ie2 = r4.z * c4.z;
                const float ie3 = r4.w * c4.w;
                const float* __restrict__ w0 = W1 + (e + 0) * NA + a0;  // uniform -> s_load
                const float* __restrict__ w1r = W1 + (e + 1) * NA + a0;
                const float* __restrict__ w2r = W1 + (e + 2) * NA + a0;
                const float* __restrict__ w3r = W1 + (e + 3) * NA + a0;
                #pragma unroll
                for (int a = 0; a < 32; ++a) {
                    h[a] = fmaf(ie0, w0[a],  h[a]);
                    h[a] = fmaf(ie1, w1r[a], h[a]);
                    h[a] = fmaf(ie2, w2r[a], h[a]);
                    h[a] = fmaf(ie3, w3r[a], h[a]);
                }
            }
            #pragma unroll
            for (int a = 0; a < 32; ++a)
                logit = fmaf(fmaxf(h[a], 0.0f), w2[a0 + a], logit);
        }
        if (p < NP) s_l[p] = logit;
    }
    __syncthreads();

    // ---- phase 2: softmax over the 496 pair logits ----
    float m = -1e30f;
    for (int p = tid; p < NP; p += 256) m = fmaxf(m, s_l[p]);
    #pragma unroll
    for (int off = 32; off > 0; off >>= 1) m = fmaxf(m, __shfl_xor(m, off));
    if (lane == 0) s_red_m[wv] = m;
    __syncthreads();
    m = fmaxf(fmaxf(s_red_m[0], s_red_m[1]), fmaxf(s_red_m[2], s_red_m[3]));

    const float v0 = expf(s_l[tid] - m);
    const float v1 = (tid < NP - 256) ? expf(s_l[tid + 256] - m) : 0.0f;
    float sum = v0 + v1;
    #pragma unroll
    for (int off = 32; off > 0; off >>= 1) sum += __shfl_xor(sum, off);
    if (lane == 0) s_red_s[wv] = sum;
    __syncthreads();
    sum = s_red_s[0] + s_red_s[1] + s_red_s[2] + s_red_s[3];
    const float inv = 1.0f / sum;

    float* __restrict__ attn_b = attn + (size_t)b * NP;
    const float a0w = v0 * inv;
    s_l[tid] = a0w;
    attn_b[tid] = a0w;
    if (tid < NP - 256) {
        const float a1w = v1 * inv;
        s_l[tid + 256] = a1w;
        attn_b[tid + 256] = a1w;
    }
    __syncthreads();

    // ---- phase 3: out[e] = sum_p attn_p * x[r][e]*x[c][e]. lane = e ----
    float acc = 0.0f;
    for (int p = wv; p < NP; p += 4) {
        const float ap = s_l[p];                 // wave-uniform broadcast
        const int r = s_r[p];
        const int c = s_c[p];
        acc = fmaf(ap * xs[r * XS + lane], xs[c * XS + lane], acc);
    }
    s_acc[wv][lane] = acc;
    __syncthreads();
    if (tid < NE) {
        out[(size_t)b * NE + tid] =
            s_acc[0][tid] + s_acc[1][tid] + s_acc[2][tid] + s_acc[3][tid];
    }
}

extern "C" void kernel_launch(void* const* d_in, const int* in_sizes, int n_in,
                              void* d_out, int out_size, void* d_ws, size_t ws_size,
                              hipStream_t stream) {
    const float* x  = (const float*)d_in[0];
    const float* W1 = (const float*)d_in[1];
    const float* b1 = (const float*)d_in[2];
    const float* w2 = (const float*)d_in[3];
    const float* b2 = (const float*)d_in[4];

    const int B = in_sizes[0] / (NF * NE);     // 2048
    float* out_p  = (float*)d_out;             // (B,1,64) flat
    float* attn_p = (float*)d_out + (size_t)B * NE;  // (B,496,1) flat

    afm_fwd<<<B, 256, 0, stream>>>(x, W1, b1, w2, b2, out_p, attn_p);
}

// Round 3
// 38.471 us; speedup vs baseline: 2.8969x; 2.8969x over previous
//
#include <hip/hip_runtime.h>
#include <math.h>

#define NF 32
#define NE 64
#define NA 64
#define NP 496
#define XS 68   // padded LDS row stride (floats): 272B = 17*16, keeps float4 alignment

typedef __attribute__((ext_vector_type(8))) _Float16 f16x8;
typedef __attribute__((ext_vector_type(4))) float    f32x4;

__global__ __launch_bounds__(256, 4) void afm_fwd(
    const float* __restrict__ x,    // (B,32,64)
    const float* __restrict__ W1,   // (64,64)
    const float* __restrict__ b1,   // (64)
    const float* __restrict__ w2,   // (64,1)
    const float* __restrict__ b2,   // (1)
    float* __restrict__ out,        // (B,64)
    float* __restrict__ attn)       // (B,496)
{
    const int b     = blockIdx.x;
    const int tid   = threadIdx.x;
    const int lane  = tid & 63;
    const int wv    = tid >> 6;
    const int nlane = lane & 15;    // MFMA M/N lane index
    const int g     = lane >> 4;    // MFMA k-group / C-row group

    __shared__ __align__(16) float xs[NF * XS];     // 8704 B
    __shared__ float s_l[512];                      // logits -> attn weights
    __shared__ unsigned char s_r[512], s_c[512];
    __shared__ float s_red_m[4], s_red_s[4];
    __shared__ __align__(16) float s_accv[4][NE];   // phase-3 partial sums

    // ---- stage x[b] into LDS (padded rows) ----
    const float* __restrict__ xb = x + (size_t)b * (NF * NE);
    for (int i = tid; i < NF * NE; i += 256) {
        xs[(i >> 6) * XS + (i & 63)] = xb[i];
    }
    // ---- pair index table (row-major triu k=1, matches np.triu_indices) ----
    for (int p = tid; p < 512; p += 256) {
        int pp = (p < NP) ? p : 0;
        int r = 0;
        while (pp >= 31 - r) { pp -= 31 - r; ++r; }
        s_r[p] = (unsigned char)r;
        s_c[p] = (unsigned char)(r + 1 + pp);
    }

    // ---- W1 B-fragments (f16), shared k-enumeration k = 32*s + 8*g + j ----
    f16x8 bf[2][4];
    #pragma unroll
    for (int s = 0; s < 2; ++s)
        #pragma unroll
        for (int nt = 0; nt < 4; ++nt)
            #pragma unroll
            for (int j = 0; j < 8; ++j)
                bf[s][nt][j] = (_Float16)W1[(s * 32 + g * 8 + j) * NA + nt * 16 + nlane];

    float b1v[4], w2v[4];
    #pragma unroll
    for (int nt = 0; nt < 4; ++nt) {
        b1v[nt] = b1[nt * 16 + nlane];
        w2v[nt] = w2[nt * 16 + nlane];
    }
    const float bias2 = b2[0];
    __syncthreads();

    // ---- phase 1: logits via fp16 MFMA. 31 p-tiles of 16; wave -> tiles w, w+4, ... ----
    for (int t = wv; t < 31; t += 4) {
        const int p0 = t * 16;
        const int r = s_r[p0 + nlane];
        const int c = s_c[p0 + nlane];
        const float* xr = xs + r * XS + (g << 3);
        const float* xc = xs + c * XS + (g << 3);

        f16x8 af[2];
        #pragma unroll
        for (int s = 0; s < 2; ++s) {
            const float4 ra = *(const float4*)(xr + s * 32);
            const float4 rb = *(const float4*)(xr + s * 32 + 4);
            const float4 ca = *(const float4*)(xc + s * 32);
            const float4 cb = *(const float4*)(xc + s * 32 + 4);
            af[s][0] = (_Float16)(ra.x * ca.x);
            af[s][1] = (_Float16)(ra.y * ca.y);
            af[s][2] = (_Float16)(ra.z * ca.z);
            af[s][3] = (_Float16)(ra.w * ca.w);
            af[s][4] = (_Float16)(rb.x * cb.x);
            af[s][5] = (_Float16)(rb.y * cb.y);
            af[s][6] = (_Float16)(rb.z * cb.z);
            af[s][7] = (_Float16)(rb.w * cb.w);
        }

        f32x4 acc[4];
        #pragma unroll
        for (int nt = 0; nt < 4; ++nt) acc[nt] = (f32x4)0.0f;
        #pragma unroll
        for (int s = 0; s < 2; ++s)
            #pragma unroll
            for (int nt = 0; nt < 4; ++nt)
                acc[nt] = __builtin_amdgcn_mfma_f32_16x16x32_f16(af[s], bf[s][nt], acc[nt], 0, 0, 0);

        // epilogue: logit[row] = b2 + sum_a relu(acc + b1[a]) * w2[a]
        float partial[4] = {0.f, 0.f, 0.f, 0.f};
        #pragma unroll
        for (int nt = 0; nt < 4; ++nt)
            #pragma unroll
            for (int reg = 0; reg < 4; ++reg) {
                const float h = acc[nt][reg] + b1v[nt];
                partial[reg] = fmaf(fmaxf(h, 0.0f), w2v[nt], partial[reg]);
            }
        #pragma unroll
        for (int off = 1; off < 16; off <<= 1)
            #pragma unroll
            for (int reg = 0; reg < 4; ++reg)
                partial[reg] += __shfl_xor(partial[reg], off);
        if (nlane == 0) {
            #pragma unroll
            for (int reg = 0; reg < 4; ++reg)
                s_l[p0 + g * 4 + reg] = partial[reg] + bias2;   // C row = 4g+reg
        }
    }
    __syncthreads();

    // ---- phase 2: softmax over the 496 pair logits ----
    float m = -1e30f;
    for (int p = tid; p < NP; p += 256) m = fmaxf(m, s_l[p]);
    #pragma unroll
    for (int off = 32; off > 0; off >>= 1) m = fmaxf(m, __shfl_xor(m, off));
    if (lane == 0) s_red_m[wv] = m;
    __syncthreads();
    m = fmaxf(fmaxf(s_red_m[0], s_red_m[1]), fmaxf(s_red_m[2], s_red_m[3]));

    const float v0 = expf(s_l[tid] - m);
    const float v1 = (tid < NP - 256) ? expf(s_l[tid + 256] - m) : 0.0f;
    float sum = v0 + v1;
    #pragma unroll
    for (int off = 32; off > 0; off >>= 1) sum += __shfl_xor(sum, off);
    if (lane == 0) s_red_s[wv] = sum;
    __syncthreads();
    sum = s_red_s[0] + s_red_s[1] + s_red_s[2] + s_red_s[3];
    const float inv = 1.0f / sum;

    float* __restrict__ attn_b = attn + (size_t)b * NP;
    const float a0w = v0 * inv;
    s_l[tid] = a0w;
    attn_b[tid] = a0w;
    if (tid < NP - 256) {
        const float a1w = v1 * inv;
        s_l[tid + 256] = a1w;
        attn_b[tid + 256] = a1w;
    }
    __syncthreads();

    // ---- phase 3: out[e] = sum_p attn_p * x[r][e]*x[c][e]. 4 pairs/iter/wave ----
    // lane group g handles pair base+g; lane&15 handles e-quad (nlane*4..+3)
    float4 acc4 = make_float4(0.f, 0.f, 0.f, 0.f);
    const int pbase = wv * 124;
    for (int it = 0; it < 31; ++it) {
        const int p = pbase + it * 4 + g;
        const float ap = s_l[p];                       // broadcast within group
        const int r = s_r[p];
        const int c = s_c[p];
        const float4 xr4 = *(const float4*)(xs + r * XS + (nlane << 2));
        const float4 xc4 = *(const float4*)(xs + c * XS + (nlane << 2));
        acc4.x = fmaf(ap * xr4.x, xc4.x, acc4.x);
        acc4.y = fmaf(ap * xr4.y, xc4.y, acc4.y);
        acc4.z = fmaf(ap * xr4.z, xc4.z, acc4.z);
        acc4.w = fmaf(ap * xr4.w, xc4.w, acc4.w);
    }
    #pragma unroll
    for (int off = 16; off < 64; off <<= 1) {
        acc4.x += __shfl_xor(acc4.x, off);
        acc4.y += __shfl_xor(acc4.y, off);
        acc4.z += __shfl_xor(acc4.z, off);
        acc4.w += __shfl_xor(acc4.w, off);
    }
    if (lane < 16) *(float4*)&s_accv[wv][lane << 2] = acc4;
    __syncthreads();
    if (tid < NE) {
        out[(size_t)b * NE + tid] =
            s_accv[0][tid] + s_accv[1][tid] + s_accv[2][tid] + s_accv[3][tid];
    }
}

extern "C" void kernel_launch(void* const* d_in, const int* in_sizes, int n_in,
                              void* d_out, int out_size, void* d_ws, size_t ws_size,
                              hipStream_t stream) {
    const float* x  = (const float*)d_in[0];
    const float* W1 = (const float*)d_in[1];
    const float* b1 = (const float*)d_in[2];
    const float* w2 = (const float*)d_in[3];
    const float* b2 = (const float*)d_in[4];

    const int B = in_sizes[0] / (NF * NE);     // 2048
    float* out_p  = (float*)d_out;             // (B,1,64) flat
    float* attn_p = (float*)d_out + (size_t)B * NE;  // (B,496,1) flat

    afm_fwd<<<B, 256, 0, stream>>>(x, W1, b1, w2, b2, out_p, attn_p);
}

// Round 4
// 32.856 us; speedup vs baseline: 3.3920x; 1.1709x over previous
//
#include <hip/hip_runtime.h>
#include <math.h>

#define NF 32
#define NE 64
#define NA 64
#define NP 496

typedef __attribute__((ext_vector_type(8))) _Float16 f16x8;
typedef __attribute__((ext_vector_type(4))) _Float16 f16x4;
typedef __attribute__((ext_vector_type(4))) float    f32x4;

__global__ __launch_bounds__(256, 4) void afm_fwd(
    const float* __restrict__ x,    // (B,32,64)
    const float* __restrict__ W1,   // (64,64)
    const float* __restrict__ b1,   // (64)
    const float* __restrict__ w2,   // (64,1)
    const float* __restrict__ b2,   // (1)
    float* __restrict__ out,        // (B,64)
    float* __restrict__ attn)       // (B,496)
{
    const int b     = blockIdx.x;
    const int tid   = threadIdx.x;
    const int lane  = tid & 63;
    const int wv    = tid >> 6;
    const int nlane = lane & 15;    // MFMA N-lane (pair within tile)
    const int g     = lane >> 4;    // k-group / C-row group

    // x in f16, subtiled [e>>3][row][e&7]: frag read = 1 ds_read_b128, <=2-way banks
    __shared__ _Float16 xh[8][NF][8];               // 4096 B
    __shared__ float s_l[512];                      // logits -> attn
    __shared__ unsigned char s_r[512], s_c[512];
    __shared__ float s_red_m[4], s_red_s[4];
    __shared__ __align__(16) float s_accv[4][NE];   // phase-3 per-wave partials

    // ---- stage x[b] -> f16 subtiled LDS ----
    const float* __restrict__ xb = x + (size_t)b * (NF * NE);
    #pragma unroll
    for (int k = 0; k < 2; ++k) {
        const int f   = (k * 256 + tid) * 4;        // flat float idx
        const float4 v = *(const float4*)(xb + f);
        const int row = f >> 6, e0 = f & 63;
        f16x4 hv = { (_Float16)v.x, (_Float16)v.y, (_Float16)v.z, (_Float16)v.w };
        *(f16x4*)&xh[e0 >> 3][row][e0 & 7] = hv;    // 8B-aligned ds_write_b64
    }
    // ---- pair index table (row-major triu k=1) ----
    for (int p = tid; p < 512; p += 256) {
        int pp = (p < NP) ? p : 0;
        int r = 0;
        while (pp >= 31 - r) { pp -= 31 - r; ++r; }
        s_r[p] = (unsigned char)r;
        s_c[p] = (unsigned char)(r + 1 + pp);
    }

    // ---- W1 as A-frags (a-rows in M), b1/w2 quads, all per-lane resident ----
    f16x8 w1f[2][4];
    #pragma unroll
    for (int s = 0; s < 2; ++s)
        #pragma unroll
        for (int mt = 0; mt < 4; ++mt)
            #pragma unroll
            for (int j = 0; j < 8; ++j)
                w1f[s][mt][j] = (_Float16)W1[(s * 32 + g * 8 + j) * NA + mt * 16 + nlane];

    f32x4 b1q[4], w2q[4];
    #pragma unroll
    for (int mt = 0; mt < 4; ++mt) {
        b1q[mt] = *(const f32x4*)(b1 + mt * 16 + g * 4);   // a = 16mt+4g+reg
        w2q[mt] = *(const f32x4*)(w2 + mt * 16 + g * 4);
    }
    const float bias2 = b2[0];
    __syncthreads();

    // ---- phase 1: logits. C' = W1^T(A) x inner^T(B): row=a-part, col=pair ----
    for (int t = wv; t < 31; t += 4) {
        const int p0 = t << 4;
        const int r = s_r[p0 + nlane];
        const int c = s_c[p0 + nlane];

        f16x8 af[2];
        #pragma unroll
        for (int s = 0; s < 2; ++s) {
            const f16x8 xr8 = *(const f16x8*)&xh[4 * s + g][r][0];
            const f16x8 xc8 = *(const f16x8*)&xh[4 * s + g][c][0];
            af[s] = xr8 * xc8;                      // v_pk_mul_f16
        }

        f32x4 acc[4];
        #pragma unroll
        for (int mt = 0; mt < 4; ++mt) acc[mt] = b1q[mt];   // b1 folded into init
        #pragma unroll
        for (int s = 0; s < 2; ++s)
            #pragma unroll
            for (int mt = 0; mt < 4; ++mt)
                acc[mt] = __builtin_amdgcn_mfma_f32_16x16x32_f16(w1f[s][mt], af[s], acc[mt], 0, 0, 0);

        // per lane: 16 a-values (a = 16mt+4g+reg); relu+w2 dot, then 2-shuffle g-reduce
        float logit = 0.0f;
        #pragma unroll
        for (int mt = 0; mt < 4; ++mt) {
            logit = fmaf(fmaxf(acc[mt][0], 0.0f), w2q[mt][0], logit);
            logit = fmaf(fmaxf(acc[mt][1], 0.0f), w2q[mt][1], logit);
            logit = fmaf(fmaxf(acc[mt][2], 0.0f), w2q[mt][2], logit);
            logit = fmaf(fmaxf(acc[mt][3], 0.0f), w2q[mt][3], logit);
        }
        logit += __shfl_xor(logit, 16);
        logit += __shfl_xor(logit, 32);
        if (lane < 16) s_l[p0 + lane] = logit + bias2;
    }
    __syncthreads();

    // ---- phase 2: softmax over 496 logits ----
    float m = -1e30f;
    for (int p = tid; p < NP; p += 256) m = fmaxf(m, s_l[p]);
    #pragma unroll
    for (int off = 32; off > 0; off >>= 1) m = fmaxf(m, __shfl_xor(m, off));
    if (lane == 0) s_red_m[wv] = m;
    __syncthreads();
    m = fmaxf(fmaxf(s_red_m[0], s_red_m[1]), fmaxf(s_red_m[2], s_red_m[3]));

    const float v0 = expf(s_l[tid] - m);
    const float v1 = (tid < NP - 256) ? expf(s_l[tid + 256] - m) : 0.0f;
    float sum = v0 + v1;
    #pragma unroll
    for (int off = 32; off > 0; off >>= 1) sum += __shfl_xor(sum, off);
    if (lane == 0) s_red_s[wv] = sum;
    __syncthreads();
    sum = s_red_s[0] + s_red_s[1] + s_red_s[2] + s_red_s[3];
    const float inv = 1.0f / sum;

    float* __restrict__ attn_b = attn + (size_t)b * NP;
    const float a0w = v0 * inv;
    s_l[tid] = a0w;
    attn_b[tid] = a0w;
    if (tid < NP - 256) {
        const float a1w = v1 * inv;
        s_l[tid + 256] = a1w;
        attn_b[tid + 256] = a1w;
    }
    __syncthreads();

    // ---- phase 3: out[e] = sum_p attn_p * inner[p][e], fused tile-recompute ----
    float oacc[2][8] = {{0}};
    for (int t = wv; t < 31; t += 4) {
        const int p0 = t << 4;
        const float ap = s_l[p0 + nlane];
        const int r = s_r[p0 + nlane];
        const int c = s_c[p0 + nlane];
        #pragma unroll
        for (int s = 0; s < 2; ++s) {
            const f16x8 xr8 = *(const f16x8*)&xh[4 * s + g][r][0];
            const f16x8 xc8 = *(const f16x8*)&xh[4 * s + g][c][0];
            const f16x8 pr = xr8 * xc8;
            #pragma unroll
            for (int j = 0; j < 8; ++j)
                oacc[s][j] = fmaf(ap, (float)pr[j], oacc[s][j]);   // e = 32s+8g+j
        }
    }
    #pragma unroll
    for (int off = 1; off < 16; off <<= 1)
        #pragma unroll
        for (int s = 0; s < 2; ++s)
            #pragma unroll
            for (int j = 0; j < 8; ++j)
                oacc[s][j] += __shfl_xor(oacc[s][j], off);
    if (nlane == 0) {
        #pragma unroll
        for (int s = 0; s < 2; ++s) {
            f32x4 q0 = { oacc[s][0], oacc[s][1], oacc[s][2], oacc[s][3] };
            f32x4 q1 = { oacc[s][4], oacc[s][5], oacc[s][6], oacc[s][7] };
            *(f32x4*)&s_accv[wv][32 * s + 8 * g]     = q0;
            *(f32x4*)&s_accv[wv][32 * s + 8 * g + 4] = q1;
        }
    }
    __syncthreads();
    if (tid < NE) {
        out[(size_t)b * NE + tid] =
            s_accv[0][tid] + s_accv[1][tid] + s_accv[2][tid] + s_accv[3][tid];
    }
}

extern "C" void kernel_launch(void* const* d_in, const int* in_sizes, int n_in,
                              void* d_out, int out_size, void* d_ws, size_t ws_size,
                              hipStream_t stream) {
    const float* x  = (const float*)d_in[0];
    const float* W1 = (const float*)d_in[1];
    const float* b1 = (const float*)d_in[2];
    const float* w2 = (const float*)d_in[3];
    const float* b2 = (const float*)d_in[4];

    const int B = in_sizes[0] / (NF * NE);     // 2048
    float* out_p  = (float*)d_out;             // (B,1,64) flat
    float* attn_p = (float*)d_out + (size_t)B * NE;  // (B,496,1) flat

    afm_fwd<<<B, 256, 0, stream>>>(x, W1, b1, w2, b2, out_p, attn_p);
}